// Round 13
// baseline (269.063 us; speedup 1.0000x reference)
//
#include <hip/hip_runtime.h>

// GAT layer, CSR + single-pass softmax + MFMA linear. N=100000, E=1.6M, DIN=128, H=4, D=16.
// ROUND 13 = round-12 source + (A) k_agg serial loop scalarized via
// readfirstlane (wave-uniform gather base -> SGPR, kills ds_bpermute + vector
// 64b addr math), (B) histogram re-fused into k_linear (R5-R9 proven config).

#define DIN 128
#define HD  64
#define NH  4

typedef __attribute__((ext_vector_type(8))) short short8;
typedef __attribute__((ext_vector_type(4))) float f32x4;

__device__ __forceinline__ float leaky02(float v) { return v > 0.f ? v : 0.2f * v; }

__device__ __forceinline__ float bf2f(unsigned short u) {
  union { unsigned u32; float f; } c; c.u32 = ((unsigned)u) << 16; return c.f;
}
__device__ __forceinline__ unsigned short f2bf(float f) {
  union { float f; unsigned u; } c; c.f = f;
  unsigned r = c.u + 0x7FFFu + ((c.u >> 16) & 1u);  // RNE
  return (unsigned short)(r >> 16);
}
__device__ __forceinline__ unsigned cvt_pk_bf16(float lo, float hi) {
  unsigned r;
  asm("v_cvt_pk_bf16_f32 %0, %1, %2" : "=v"(r) : "v"(lo), "v"(hi));
  return r;  // low16 = bf16(lo), high16 = bf16(hi)
}

// ---------------- K0: fold W_att through W_lin ----------------
__global__ void k_wfold(const float* __restrict__ Wlin, const float* __restrict__ Watt,
                        float* __restrict__ Wfold) {
  for (int i = threadIdx.x; i < DIN * 8; i += 256) {
    int k = i >> 3, c = i & 7;
    int head = c & 3, dsth = (c >= 4) ? 16 : 0;
    float s = 0.f;
#pragma unroll
    for (int d = 0; d < 16; ++d)
      s += Wlin[k * HD + head * 16 + d] * Watt[head * 32 + dsth + d];
    Wfold[i] = s;
  }
}

// ---------------- K1: MFMA linear, LDS-staged epilogue + fused histogram ----------------
// Block: 512 thr (8 waves), 128 rows (8 waves x 16 rows).
#define BTP 136
__global__ __launch_bounds__(512)
void k_linear(const float* __restrict__ x, const float* __restrict__ Wlin,
              const float* __restrict__ Wfold,
              unsigned short* __restrict__ hb,
              float* __restrict__ a_src, float* __restrict__ a_dst,
              int N,
              const int* __restrict__ ei, int* __restrict__ deg, int E) {
  __shared__ __align__(16) unsigned short BT[80 * BTP];   // 21.25 KiB weights
  __shared__ __align__(16) unsigned short OT[8][16 * 68]; // 17 KiB C-staging (pad 68)
  __shared__ __align__(16) float AT[8][16 * 8];           // 4 KiB att-staging
  const int tid = threadIdx.x;
  const int lane = tid & 63;
  const int wid  = tid >> 6;  // 0..7

  // stage transposed bf16 weights
  for (int i = tid; i < DIN * HD; i += 512) {
    int k = i >> 6, c = i & 63;
    BT[c * BTP + k] = f2bf(Wlin[i]);
  }
  for (int i = tid; i < DIN * 8; i += 512) {
    int k = i >> 3, c = i & 7;
    BT[(64 + c) * BTP + k] = f2bf(Wfold[i]);
    BT[(72 + c) * BTP + k] = 0;
  }
  __syncthreads();

  // per-wave B fragments in VGPRs: 5 col-tiles x 4 k-tiles
  short8 bf[5][4];
#pragma unroll
  for (int ct = 0; ct < 5; ++ct) {
    const int c = (ct < 4) ? (ct * 16 + (lane & 15)) : (64 + (lane & 15));
#pragma unroll
    for (int kt = 0; kt < 4; ++kt)
      bf[ct][kt] = *(const short8*)(&BT[c * BTP + kt * 32 + (lane >> 4) * 8]);
  }

  const int row0 = blockIdx.x * 128 + wid * 16;
  if (row0 < N) {
    // A: 16 rows x 128 k. lane: row = l&15, k = kt*32 + (l>>4)*8 + j
    const int r = min(row0 + (lane & 15), N - 1);
    const float* xp = x + (size_t)r * DIN + ((lane >> 4) * 8);
    float4 xv[8];
#pragma unroll
    for (int kt = 0; kt < 4; ++kt) {
      xv[kt * 2 + 0] = *(const float4*)(xp + kt * 32);
      xv[kt * 2 + 1] = *(const float4*)(xp + kt * 32 + 4);
    }
    short8 af[4];
#pragma unroll
    for (int kt = 0; kt < 4; ++kt) {
      unsigned* ap = (unsigned*)&af[kt];
      const float4 a = xv[kt * 2], b = xv[kt * 2 + 1];
      ap[0] = cvt_pk_bf16(a.x, a.y);
      ap[1] = cvt_pk_bf16(a.z, a.w);
      ap[2] = cvt_pk_bf16(b.x, b.y);
      ap[3] = cvt_pk_bf16(b.z, b.w);
    }
    f32x4 acc[5] = {{0,0,0,0},{0,0,0,0},{0,0,0,0},{0,0,0,0},{0,0,0,0}};
#pragma unroll
    for (int ct = 0; ct < 5; ++ct)
#pragma unroll
      for (int kt = 0; kt < 4; ++kt)
        acc[ct] = __builtin_amdgcn_mfma_f32_16x16x32_bf16(af[kt], bf[ct][kt], acc[ct], 0, 0, 0);

    // --- LDS-staged epilogue (wave-private, no barrier) ---
    // C/D layout: col = lane&15, row = (lane>>4)*4 + j
    const int c0 = lane & 15;
    const int r0 = (lane >> 4) * 4;
#pragma unroll
    for (int j = 0; j < 4; ++j) {
#pragma unroll
      for (int ct = 0; ct < 4; ++ct)
        OT[wid][(r0 + j) * 68 + ct * 16 + c0] = f2bf(acc[ct][j]);
      if (c0 < 8) AT[wid][(r0 + j) * 8 + c0] = acc[4][j];
    }
    // coalesced writeback: 2 rows (256B) per instruction
    unsigned* hbu = (unsigned*)(hb + (size_t)row0 * HD);
#pragma unroll
    for (int it = 0; it < 8; ++it) {
      const int rr = it * 2 + (lane >> 5);
      const int cw = lane & 31;
      const unsigned v = *(const unsigned*)&OT[wid][rr * 68 + cw * 2];
      if (row0 + rr < N) hbu[rr * 32 + cw] = v;
    }
    {
      const int rr = lane >> 2, cc = lane & 3;
      if (row0 + rr < N) {
        a_src[(row0 + rr) * 4 + cc] = AT[wid][rr * 8 + cc];
        a_dst[(row0 + rr) * 4 + cc] = AT[wid][rr * 8 + 4 + cc];
      }
    }
  }

  // fused degree histogram over this block's edge slice (R5-R9 proven)
  const int per = (E + gridDim.x - 1) / gridDim.x;
  const int e0 = blockIdx.x * per;
  const int e1 = min(e0 + per, E);
  for (int e = e0 + tid; e < e1; e += 512)
    atomicAdd(&deg[ei[e]], 1);
}

// ---------------- K3a: per-block exclusive scan ----------------
__global__ void k_scanA(const int* __restrict__ deg, int* __restrict__ offs,
                        int* __restrict__ partials, int N) {
  __shared__ int wsum[16];
  const int tid = threadIdx.x, lane = tid & 63, wv = tid >> 6;
  int i = blockIdx.x * 1024 + tid;
  int v = (i < N) ? deg[i] : 0;
  int sc = v;
#pragma unroll
  for (int s = 1; s < 64; s <<= 1) {
    int t = __shfl_up(sc, s, 64);
    if (lane >= s) sc += t;
  }
  if (lane == 63) wsum[wv] = sc;
  __syncthreads();
  if (wv == 0 && lane < 16) {
    int w = wsum[lane];
    int s2 = w;
#pragma unroll
    for (int s = 1; s < 16; s <<= 1) {
      int t = __shfl_up(s2, s, 64);
      if (lane >= s) s2 += t;
    }
    wsum[lane] = s2 - w;
  }
  __syncthreads();
  int excl = sc - v + wsum[wv];
  if (i < N) offs[i] = excl;
  if (tid == 1023) partials[blockIdx.x] = excl + v;
}

// ---------------- K3b: add block bases ----------------
__global__ void k_scanB(int* __restrict__ offs, const int* __restrict__ partials, int N) {
  __shared__ int sbase;
  const int tid = threadIdx.x, b = blockIdx.x;
  if (tid < 64) {
    int acc = 0;
    for (int j = tid; j < b; j += 64) acc += partials[j];
#pragma unroll
    for (int s = 32; s >= 1; s >>= 1) acc += __shfl_xor(acc, s, 64);
    if (tid == 0) sbase = acc;
  }
  __syncthreads();
  int i = b * 1024 + tid;
  if (i < N) offs[i] += sbase;
}

// ---------------- K4: bucketed CSR scatter (plain store) ----------------
__global__ void k_scatter(const int* __restrict__ ei, int* __restrict__ offs,
                          int* __restrict__ csr, int E, int lo, int hi) {
  int stride = gridDim.x * blockDim.x;
  for (int e = blockIdx.x * blockDim.x + threadIdx.x; e < E; e += stride) {
    int s = ei[e];
    if (s >= lo && s < hi) {
      int d = ei[E + e];
      int p = atomicAdd(&offs[s], 1);
      csr[p] = d;
    }
  }
}

// ---------------- K5: aggregate, scalarized serial loop ----------------
__global__ __launch_bounds__(256)
void k_agg(const int* __restrict__ offs_end, const int* __restrict__ deg,
           const int* __restrict__ csr, const float4* __restrict__ a_src4,
           const float4* __restrict__ a_dst4,
           const unsigned short* __restrict__ hb,
           float* __restrict__ out, int N) {
  __shared__ float als[4][64 * NH];
  const int lane = threadIdx.x & 63;
  const int wid  = threadIdx.x >> 6;
  const int hh = lane >> 4;
  const int wstride = gridDim.x * 4;

  for (int n0 = blockIdx.x * 4 + wid; n0 < N; n0 += wstride) {
    const int n   = __builtin_amdgcn_readfirstlane(n0);
    const int end = __builtin_amdgcn_readfirstlane(offs_end[n]);
    const int dg  = __builtin_amdgcn_readfirstlane(deg[n]);
    const int beg = end - dg;
    const float4 asv = a_src4[n];

    float s0 = 0.f, s1 = 0.f, s2 = 0.f, s3 = 0.f;
    float acc0 = 0.f, acc1 = 0.f;
    for (int base = beg; base < end; base += 64) {
      const int cnt = __builtin_amdgcn_readfirstlane(min(64, end - base));
      const bool act = lane < cnt;
      const int d = csr[act ? base + lane : beg];
      const float4 ad = a_dst4[d];
      const float p0 = act ? __expf(leaky02(asv.x + ad.x)) : 0.f;
      const float p1 = act ? __expf(leaky02(asv.y + ad.y)) : 0.f;
      const float p2 = act ? __expf(leaky02(asv.z + ad.z)) : 0.f;
      const float p3 = act ? __expf(leaky02(asv.w + ad.w)) : 0.f;
      s0 += p0; s1 += p1; s2 += p2; s3 += p3;
      *(float4*)&als[wid][lane * 4] = make_float4(p0, p1, p2, p3);

      int j = 0;
      for (; j + 8 <= cnt; j += 8) {  // scalar row bases, 8 gathers in flight
        int dds[8];
#pragma unroll
        for (int u = 0; u < 8; ++u)
          dds[u] = __builtin_amdgcn_readfirstlane(csr[base + j + u]);
        float hv[8];
#pragma unroll
        for (int u = 0; u < 8; ++u) hv[u] = bf2f(hb[(size_t)dds[u] * HD + lane]);
#pragma unroll
        for (int u = 0; u < 8; ++u) {
          const float av = als[wid][(j + u) * 4 + hh];
          if (u & 1) acc1 = fmaf(av, hv[u], acc1);
          else       acc0 = fmaf(av, hv[u], acc0);
        }
      }
      for (; j < cnt; ++j) {
        const int dd_ = __builtin_amdgcn_readfirstlane(csr[base + j]);
        const float av = als[wid][j * 4 + hh];
        acc0 = fmaf(av, bf2f(hb[(size_t)dd_ * HD + lane]), acc0);
      }
    }
#pragma unroll
    for (int s = 1; s < 64; s <<= 1) {
      s0 += __shfl_xor(s0, s, 64); s1 += __shfl_xor(s1, s, 64);
      s2 += __shfl_xor(s2, s, 64); s3 += __shfl_xor(s3, s, 64);
    }
    const float sh = (hh == 0) ? s0 : (hh == 1) ? s1 : (hh == 2) ? s2 : s3;
    out[(size_t)n * HD + lane] = (acc0 + acc1) * (1.f / (sh + 1e-16f));
  }
}

extern "C" void kernel_launch(void* const* d_in, const int* in_sizes, int n_in,
                              void* d_out, int out_size, void* d_ws, size_t ws_size,
                              hipStream_t stream) {
  const float* x    = (const float*)d_in[0];
  const int*   ei   = (const int*)d_in[1];
  const float* Wlin = (const float*)d_in[2];
  const float* Watt = (const float*)d_in[3];
  float* out = (float*)d_out;

  const int N = in_sizes[0] / DIN;
  const int E = in_sizes[1] / 2;

  char* ws = (char*)d_ws;
  size_t off = 0;
  unsigned short* hb = (unsigned short*)(ws + off); off += (size_t)N * HD * sizeof(unsigned short);
  float* a_src  = (float*)(ws + off); off += (size_t)N * NH * sizeof(float);
  float* a_dst  = (float*)(ws + off); off += (size_t)N * NH * sizeof(float);
  int*   deg    = (int*)(ws + off);   off += (size_t)N * sizeof(int);
  int*   offs   = (int*)(ws + off);   off += ((size_t)N + 1) * sizeof(int);
  int*   csr    = (int*)(ws + off);   off += (size_t)E * sizeof(int);
  int*   parts  = (int*)(ws + off);   off += 128 * sizeof(int);
  float* wfold  = (float*)(ws + off); off += DIN * 8 * sizeof(float);

  hipMemsetAsync(deg, 0, (size_t)N * sizeof(int), stream);

  hipLaunchKernelGGL(k_wfold, dim3(1), dim3(256), 0, stream, Wlin, Watt, wfold);

  hipLaunchKernelGGL(k_linear, dim3((N + 127) / 128), dim3(512), 0, stream,
                     x, Wlin, wfold, hb, a_src, a_dst, N, ei, deg, E);

  const int SB = (N + 1023) / 1024;
  hipLaunchKernelGGL(k_scanA, dim3(SB), dim3(1024), 0, stream, deg, offs, parts, N);
  hipLaunchKernelGGL(k_scanB, dim3(SB), dim3(1024), 0, stream, offs, parts, N);

  const int NBUCKET = 2;
  const int step = (N + NBUCKET - 1) / NBUCKET;
  for (int b = 0; b < NBUCKET; ++b) {
    hipLaunchKernelGGL(k_scatter, dim3(2048), dim3(256), 0, stream,
                       ei, offs, csr, E, b * step, min(N, (b + 1) * step));
  }
  // offs[n] == segment end now
  hipLaunchKernelGGL(k_agg, dim3(4096), dim3(256), 0, stream,
                     offs, deg, csr, (const float4*)a_src, (const float4*)a_dst, hb, out, N);
}

// Round 14
// 223.315 us; speedup vs baseline: 1.2049x; 1.2049x over previous
//
#include <hip/hip_runtime.h>

// GAT layer, CSR + single-pass softmax + MFMA linear. N=100000, E=1.6M, DIN=128, H=4, D=16.
// ROUND 14 = round-13 source + (A) k_linear: x loads hoisted ABOVE weight
// staging/barrier (overlap HBM latency with staging; geometry untouched),
// (B) k_scatter: ONE dispatch, XCD-aware buckets (bid&7), 8 src-ranges so
// each csr window is dirtied by a single XCD's L2.

#define DIN 128
#define HD  64
#define NH  4

typedef __attribute__((ext_vector_type(8))) short short8;
typedef __attribute__((ext_vector_type(4))) float f32x4;

__device__ __forceinline__ float leaky02(float v) { return v > 0.f ? v : 0.2f * v; }

__device__ __forceinline__ float bf2f(unsigned short u) {
  union { unsigned u32; float f; } c; c.u32 = ((unsigned)u) << 16; return c.f;
}
__device__ __forceinline__ unsigned short f2bf(float f) {
  union { float f; unsigned u; } c; c.f = f;
  unsigned r = c.u + 0x7FFFu + ((c.u >> 16) & 1u);  // RNE
  return (unsigned short)(r >> 16);
}
__device__ __forceinline__ unsigned cvt_pk_bf16(float lo, float hi) {
  unsigned r;
  asm("v_cvt_pk_bf16_f32 %0, %1, %2" : "=v"(r) : "v"(lo), "v"(hi));
  return r;  // low16 = bf16(lo), high16 = bf16(hi)
}

// ---------------- K0: fold W_att through W_lin ----------------
__global__ void k_wfold(const float* __restrict__ Wlin, const float* __restrict__ Watt,
                        float* __restrict__ Wfold) {
  for (int i = threadIdx.x; i < DIN * 8; i += 256) {
    int k = i >> 3, c = i & 7;
    int head = c & 3, dsth = (c >= 4) ? 16 : 0;
    float s = 0.f;
#pragma unroll
    for (int d = 0; d < 16; ++d)
      s += Wlin[k * HD + head * 16 + d] * Watt[head * 32 + dsth + d];
    Wfold[i] = s;
  }
}

// ---------------- K1: MFMA linear, x-prefetch + LDS-staged epilogue + fused hist ----------------
// Block: 512 thr (8 waves), 128 rows (8 waves x 16 rows).
#define BTP 136
__global__ __launch_bounds__(512)
void k_linear(const float* __restrict__ x, const float* __restrict__ Wlin,
              const float* __restrict__ Wfold,
              unsigned short* __restrict__ hb,
              float* __restrict__ a_src, float* __restrict__ a_dst,
              int N,
              const int* __restrict__ ei, int* __restrict__ deg, int E) {
  __shared__ __align__(16) unsigned short BT[80 * BTP];   // 21.25 KiB weights
  __shared__ __align__(16) unsigned short OT[8][16 * 68]; // 17 KiB C-staging (pad 68)
  __shared__ __align__(16) float AT[8][16 * 8];           // 4 KiB att-staging
  const int tid = threadIdx.x;
  const int lane = tid & 63;
  const int wid  = tid >> 6;  // 0..7

  const int row0 = blockIdx.x * 128 + wid * 16;
  const bool rowok = row0 < N;

  // ---- (A) issue x loads FIRST: HBM latency overlaps the staging phase ----
  float4 xv[8];
  if (rowok) {
    const int r = min(row0 + (lane & 15), N - 1);
    const float* xp = x + (size_t)r * DIN + ((lane >> 4) * 8);
#pragma unroll
    for (int kt = 0; kt < 4; ++kt) {
      xv[kt * 2 + 0] = *(const float4*)(xp + kt * 32);
      xv[kt * 2 + 1] = *(const float4*)(xp + kt * 32 + 4);
    }
  }

  // stage transposed bf16 weights
  for (int i = tid; i < DIN * HD; i += 512) {
    int k = i >> 6, c = i & 63;
    BT[c * BTP + k] = f2bf(Wlin[i]);
  }
  for (int i = tid; i < DIN * 8; i += 512) {
    int k = i >> 3, c = i & 7;
    BT[(64 + c) * BTP + k] = f2bf(Wfold[i]);
    BT[(72 + c) * BTP + k] = 0;
  }
  __syncthreads();

  // per-wave B fragments in VGPRs: 5 col-tiles x 4 k-tiles
  short8 bf[5][4];
#pragma unroll
  for (int ct = 0; ct < 5; ++ct) {
    const int c = (ct < 4) ? (ct * 16 + (lane & 15)) : (64 + (lane & 15));
#pragma unroll
    for (int kt = 0; kt < 4; ++kt)
      bf[ct][kt] = *(const short8*)(&BT[c * BTP + kt * 32 + (lane >> 4) * 8]);
  }

  if (rowok) {
    short8 af[4];
#pragma unroll
    for (int kt = 0; kt < 4; ++kt) {
      unsigned* ap = (unsigned*)&af[kt];
      const float4 a = xv[kt * 2], b = xv[kt * 2 + 1];
      ap[0] = cvt_pk_bf16(a.x, a.y);
      ap[1] = cvt_pk_bf16(a.z, a.w);
      ap[2] = cvt_pk_bf16(b.x, b.y);
      ap[3] = cvt_pk_bf16(b.z, b.w);
    }
    f32x4 acc[5] = {{0,0,0,0},{0,0,0,0},{0,0,0,0},{0,0,0,0},{0,0,0,0}};
#pragma unroll
    for (int ct = 0; ct < 5; ++ct)
#pragma unroll
      for (int kt = 0; kt < 4; ++kt)
        acc[ct] = __builtin_amdgcn_mfma_f32_16x16x32_bf16(af[kt], bf[ct][kt], acc[ct], 0, 0, 0);

    // --- LDS-staged epilogue (wave-private, no barrier) ---
    // C/D layout: col = lane&15, row = (lane>>4)*4 + j
    const int c0 = lane & 15;
    const int r0 = (lane >> 4) * 4;
#pragma unroll
    for (int j = 0; j < 4; ++j) {
#pragma unroll
      for (int ct = 0; ct < 4; ++ct)
        OT[wid][(r0 + j) * 68 + ct * 16 + c0] = f2bf(acc[ct][j]);
      if (c0 < 8) AT[wid][(r0 + j) * 8 + c0] = acc[4][j];
    }
    // coalesced writeback: 2 rows (256B) per instruction
    unsigned* hbu = (unsigned*)(hb + (size_t)row0 * HD);
#pragma unroll
    for (int it = 0; it < 8; ++it) {
      const int rr = it * 2 + (lane >> 5);
      const int cw = lane & 31;
      const unsigned v = *(const unsigned*)&OT[wid][rr * 68 + cw * 2];
      if (row0 + rr < N) hbu[rr * 32 + cw] = v;
    }
    {
      const int rr = lane >> 2, cc = lane & 3;
      if (row0 + rr < N) {
        a_src[(row0 + rr) * 4 + cc] = AT[wid][rr * 8 + cc];
        a_dst[(row0 + rr) * 4 + cc] = AT[wid][rr * 8 + 4 + cc];
      }
    }
  }

  // fused degree histogram over this block's edge slice
  const int per = (E + gridDim.x - 1) / gridDim.x;
  const int e0 = blockIdx.x * per;
  const int e1 = min(e0 + per, E);
  for (int e = e0 + tid; e < e1; e += 512)
    atomicAdd(&deg[ei[e]], 1);
}

// ---------------- K3a: per-block exclusive scan ----------------
__global__ void k_scanA(const int* __restrict__ deg, int* __restrict__ offs,
                        int* __restrict__ partials, int N) {
  __shared__ int wsum[16];
  const int tid = threadIdx.x, lane = tid & 63, wv = tid >> 6;
  int i = blockIdx.x * 1024 + tid;
  int v = (i < N) ? deg[i] : 0;
  int sc = v;
#pragma unroll
  for (int s = 1; s < 64; s <<= 1) {
    int t = __shfl_up(sc, s, 64);
    if (lane >= s) sc += t;
  }
  if (lane == 63) wsum[wv] = sc;
  __syncthreads();
  if (wv == 0 && lane < 16) {
    int w = wsum[lane];
    int s2 = w;
#pragma unroll
    for (int s = 1; s < 16; s <<= 1) {
      int t = __shfl_up(s2, s, 64);
      if (lane >= s) s2 += t;
    }
    wsum[lane] = s2 - w;
  }
  __syncthreads();
  int excl = sc - v + wsum[wv];
  if (i < N) offs[i] = excl;
  if (tid == 1023) partials[blockIdx.x] = excl + v;
}

// ---------------- K3b: add block bases ----------------
__global__ void k_scanB(int* __restrict__ offs, const int* __restrict__ partials, int N) {
  __shared__ int sbase;
  const int tid = threadIdx.x, b = blockIdx.x;
  if (tid < 64) {
    int acc = 0;
    for (int j = tid; j < b; j += 64) acc += partials[j];
#pragma unroll
    for (int s = 32; s >= 1; s >>= 1) acc += __shfl_xor(acc, s, 64);
    if (tid == 0) sbase = acc;
  }
  __syncthreads();
  int i = b * 1024 + tid;
  if (i < N) offs[i] += sbase;
}

// ---------------- K4: XCD-aware CSR scatter, single dispatch ----------------
// bucket = blockIdx.x & 7 (~XCD id on MI355X). Each bucket's 256-block group
// grid-strides all edges, scattering only src in [xcd*step, xcd*step+step).
// Correct for ANY block->XCD mapping; the mapping only affects locality.
__global__ void k_scatter8(const int* __restrict__ ei, int* __restrict__ offs,
                           int* __restrict__ csr, int E, int N) {
  const int xcd  = blockIdx.x & 7;
  const int grp  = blockIdx.x >> 3;
  const int ngrp = gridDim.x >> 3;
  const int step = (N + 7) >> 3;
  const int lo = xcd * step, hi = min(N, lo + step);
  const int stride = ngrp * blockDim.x;
  for (int e = grp * blockDim.x + threadIdx.x; e < E; e += stride) {
    int s = ei[e];
    if (s >= lo && s < hi) {
      int d = ei[E + e];
      int p = atomicAdd(&offs[s], 1);
      csr[p] = d;
    }
  }
}

// ---------------- K5: aggregate, scalarized serial loop ----------------
__global__ __launch_bounds__(256)
void k_agg(const int* __restrict__ offs_end, const int* __restrict__ deg,
           const int* __restrict__ csr, const float4* __restrict__ a_src4,
           const float4* __restrict__ a_dst4,
           const unsigned short* __restrict__ hb,
           float* __restrict__ out, int N) {
  __shared__ float als[4][64 * NH];
  const int lane = threadIdx.x & 63;
  const int wid  = threadIdx.x >> 6;
  const int hh = lane >> 4;
  const int wstride = gridDim.x * 4;

  for (int n0 = blockIdx.x * 4 + wid; n0 < N; n0 += wstride) {
    const int n   = __builtin_amdgcn_readfirstlane(n0);
    const int end = __builtin_amdgcn_readfirstlane(offs_end[n]);
    const int dg  = __builtin_amdgcn_readfirstlane(deg[n]);
    const int beg = end - dg;
    const float4 asv = a_src4[n];

    float s0 = 0.f, s1 = 0.f, s2 = 0.f, s3 = 0.f;
    float acc0 = 0.f, acc1 = 0.f;
    for (int base = beg; base < end; base += 64) {
      const int cnt = __builtin_amdgcn_readfirstlane(min(64, end - base));
      const bool act = lane < cnt;
      const int d = csr[act ? base + lane : beg];
      const float4 ad = a_dst4[d];
      const float p0 = act ? __expf(leaky02(asv.x + ad.x)) : 0.f;
      const float p1 = act ? __expf(leaky02(asv.y + ad.y)) : 0.f;
      const float p2 = act ? __expf(leaky02(asv.z + ad.z)) : 0.f;
      const float p3 = act ? __expf(leaky02(asv.w + ad.w)) : 0.f;
      s0 += p0; s1 += p1; s2 += p2; s3 += p3;
      *(float4*)&als[wid][lane * 4] = make_float4(p0, p1, p2, p3);

      int j = 0;
      for (; j + 8 <= cnt; j += 8) {  // scalar row bases, 8 gathers in flight
        int dds[8];
#pragma unroll
        for (int u = 0; u < 8; ++u)
          dds[u] = __builtin_amdgcn_readfirstlane(csr[base + j + u]);
        float hv[8];
#pragma unroll
        for (int u = 0; u < 8; ++u) hv[u] = bf2f(hb[(size_t)dds[u] * HD + lane]);
#pragma unroll
        for (int u = 0; u < 8; ++u) {
          const float av = als[wid][(j + u) * 4 + hh];
          if (u & 1) acc1 = fmaf(av, hv[u], acc1);
          else       acc0 = fmaf(av, hv[u], acc0);
        }
      }
      for (; j < cnt; ++j) {
        const int dd_ = __builtin_amdgcn_readfirstlane(csr[base + j]);
        const float av = als[wid][j * 4 + hh];
        acc0 = fmaf(av, bf2f(hb[(size_t)dd_ * HD + lane]), acc0);
      }
    }
#pragma unroll
    for (int s = 1; s < 64; s <<= 1) {
      s0 += __shfl_xor(s0, s, 64); s1 += __shfl_xor(s1, s, 64);
      s2 += __shfl_xor(s2, s, 64); s3 += __shfl_xor(s3, s, 64);
    }
    const float sh = (hh == 0) ? s0 : (hh == 1) ? s1 : (hh == 2) ? s2 : s3;
    out[(size_t)n * HD + lane] = (acc0 + acc1) * (1.f / (sh + 1e-16f));
  }
}

extern "C" void kernel_launch(void* const* d_in, const int* in_sizes, int n_in,
                              void* d_out, int out_size, void* d_ws, size_t ws_size,
                              hipStream_t stream) {
  const float* x    = (const float*)d_in[0];
  const int*   ei   = (const int*)d_in[1];
  const float* Wlin = (const float*)d_in[2];
  const float* Watt = (const float*)d_in[3];
  float* out = (float*)d_out;

  const int N = in_sizes[0] / DIN;
  const int E = in_sizes[1] / 2;

  char* ws = (char*)d_ws;
  size_t off = 0;
  unsigned short* hb = (unsigned short*)(ws + off); off += (size_t)N * HD * sizeof(unsigned short);
  float* a_src  = (float*)(ws + off); off += (size_t)N * NH * sizeof(float);
  float* a_dst  = (float*)(ws + off); off += (size_t)N * NH * sizeof(float);
  int*   deg    = (int*)(ws + off);   off += (size_t)N * sizeof(int);
  int*   offs   = (int*)(ws + off);   off += ((size_t)N + 1) * sizeof(int);
  int*   csr    = (int*)(ws + off);   off += (size_t)E * sizeof(int);
  int*   parts  = (int*)(ws + off);   off += 128 * sizeof(int);
  float* wfold  = (float*)(ws + off); off += DIN * 8 * sizeof(float);

  hipMemsetAsync(deg, 0, (size_t)N * sizeof(int), stream);

  hipLaunchKernelGGL(k_wfold, dim3(1), dim3(256), 0, stream, Wlin, Watt, wfold);

  hipLaunchKernelGGL(k_linear, dim3((N + 127) / 128), dim3(512), 0, stream,
                     x, Wlin, wfold, hb, a_src, a_dst, N, ei, deg, E);

  const int SB = (N + 1023) / 1024;
  hipLaunchKernelGGL(k_scanA, dim3(SB), dim3(1024), 0, stream, deg, offs, parts, N);
  hipLaunchKernelGGL(k_scanB, dim3(SB), dim3(1024), 0, stream, offs, parts, N);

  hipLaunchKernelGGL(k_scatter8, dim3(2048), dim3(256), 0, stream,
                     ei, offs, csr, E, N);

  // offs[n] == segment end now
  hipLaunchKernelGGL(k_agg, dim3(4096), dim3(256), 0, stream,
                     offs, deg, csr, (const float4*)a_src, (const float4*)a_dst, hb, out, N);
}

// Round 15
// 222.678 us; speedup vs baseline: 1.2083x; 1.0029x over previous
//
#include <hip/hip_runtime.h>

// GAT layer, CSR + single-pass softmax + MFMA linear. N=100000, E=1.6M, DIN=128, H=4, D=16.
// ROUND 15 = round-14 source + (A) k_linear: 2 row-tiles per block (R5/R8-proven
// 2-pass shape), tile-1 x loads issued during tile-0 compute; (B) wfold computed
// inline in k_linear staging (R5-proven), k_wfold kernel deleted.

#define DIN 128
#define HD  64
#define NH  4

typedef __attribute__((ext_vector_type(8))) short short8;
typedef __attribute__((ext_vector_type(4))) float f32x4;

__device__ __forceinline__ float leaky02(float v) { return v > 0.f ? v : 0.2f * v; }

__device__ __forceinline__ float bf2f(unsigned short u) {
  union { unsigned u32; float f; } c; c.u32 = ((unsigned)u) << 16; return c.f;
}
__device__ __forceinline__ unsigned short f2bf(float f) {
  union { float f; unsigned u; } c; c.f = f;
  unsigned r = c.u + 0x7FFFu + ((c.u >> 16) & 1u);  // RNE
  return (unsigned short)(r >> 16);
}
__device__ __forceinline__ unsigned cvt_pk_bf16(float lo, float hi) {
  unsigned r;
  asm("v_cvt_pk_bf16_f32 %0, %1, %2" : "=v"(r) : "v"(lo), "v"(hi));
  return r;  // low16 = bf16(lo), high16 = bf16(hi)
}

// ---------------- K1: MFMA linear, 2 tiles/block + inline wfold + fused hist ----------------
// Block: 512 thr (8 waves), 256 rows (2 tiles x 8 waves x 16 rows).
#define BTP 136
__global__ __launch_bounds__(512)
void k_linear(const float* __restrict__ x, const float* __restrict__ Wlin,
              const float* __restrict__ Watt,
              unsigned short* __restrict__ hb,
              float* __restrict__ a_src, float* __restrict__ a_dst,
              int N,
              const int* __restrict__ ei, int* __restrict__ deg, int E) {
  __shared__ __align__(16) unsigned short BT[80 * BTP];   // 21.25 KiB weights
  __shared__ __align__(16) unsigned short OT[8][16 * 68]; // 17 KiB C-staging (pad 68)
  __shared__ __align__(16) float AT[8][16 * 8];           // 4 KiB att-staging
  const int tid = threadIdx.x;
  const int lane = tid & 63;
  const int wid  = tid >> 6;  // 0..7

  const int row0_0 = blockIdx.x * 256 + wid * 16;
  const int row0_1 = row0_0 + 128;
  const bool ok0 = row0_0 < N;
  const bool ok1 = row0_1 < N;

  // tile-0 x prefetch (overlaps staging)
  float4 xv0[8];
  if (ok0) {
    const int r = min(row0_0 + (lane & 15), N - 1);
    const float* xp = x + (size_t)r * DIN + ((lane >> 4) * 8);
#pragma unroll
    for (int kt = 0; kt < 4; ++kt) {
      xv0[kt * 2 + 0] = *(const float4*)(xp + kt * 32);
      xv0[kt * 2 + 1] = *(const float4*)(xp + kt * 32 + 4);
    }
  }

  // stage transposed bf16 weights (W_lin cols 0..63)
  for (int i = tid; i < DIN * HD; i += 512) {
    int k = i >> 6, c = i & 63;
    BT[c * BTP + k] = f2bf(Wlin[i]);
  }
  // inline wfold: cols 64..71 = W_att folded through W_lin; 72..79 = zero pad
  for (int i = tid; i < DIN * 8; i += 512) {
    int k = i >> 3, c = i & 7;
    int head = c & 3, dsth = (c >= 4) ? 16 : 0;
    float s = 0.f;
#pragma unroll
    for (int d = 0; d < 16; ++d)
      s += Wlin[k * HD + head * 16 + d] * Watt[head * 32 + dsth + d];
    BT[(64 + c) * BTP + k] = f2bf(s);
    BT[(72 + c) * BTP + k] = 0;
  }
  __syncthreads();

  // per-wave B fragments: 5 col-tiles x 4 k-tiles
  short8 bf[5][4];
#pragma unroll
  for (int ct = 0; ct < 5; ++ct) {
    const int c = (ct < 4) ? (ct * 16 + (lane & 15)) : (64 + (lane & 15));
#pragma unroll
    for (int kt = 0; kt < 4; ++kt)
      bf[ct][kt] = *(const short8*)(&BT[c * BTP + kt * 32 + (lane >> 4) * 8]);
  }

  // ---- tile 0: pack A ----
  short8 af0[4];
  if (ok0) {
#pragma unroll
    for (int kt = 0; kt < 4; ++kt) {
      unsigned* ap = (unsigned*)&af0[kt];
      const float4 a = xv0[kt * 2], b = xv0[kt * 2 + 1];
      ap[0] = cvt_pk_bf16(a.x, a.y);
      ap[1] = cvt_pk_bf16(a.z, a.w);
      ap[2] = cvt_pk_bf16(b.x, b.y);
      ap[3] = cvt_pk_bf16(b.z, b.w);
    }
  }

  // tile-1 x loads: issued now, latency hidden under tile-0 MFMA + epilogue
  float4 xv1[8];
  if (ok1) {
    const int r = min(row0_1 + (lane & 15), N - 1);
    const float* xp = x + (size_t)r * DIN + ((lane >> 4) * 8);
#pragma unroll
    for (int kt = 0; kt < 4; ++kt) {
      xv1[kt * 2 + 0] = *(const float4*)(xp + kt * 32);
      xv1[kt * 2 + 1] = *(const float4*)(xp + kt * 32 + 4);
    }
  }

#pragma unroll
  for (int t = 0; t < 2; ++t) {
    const int row0 = t ? row0_1 : row0_0;
    if (row0 >= N) break;
    short8 af[4];
    if (t == 0) {
#pragma unroll
      for (int kt = 0; kt < 4; ++kt) af[kt] = af0[kt];
    } else {
#pragma unroll
      for (int kt = 0; kt < 4; ++kt) {
        unsigned* ap = (unsigned*)&af[kt];
        const float4 a = xv1[kt * 2], b = xv1[kt * 2 + 1];
        ap[0] = cvt_pk_bf16(a.x, a.y);
        ap[1] = cvt_pk_bf16(a.z, a.w);
        ap[2] = cvt_pk_bf16(b.x, b.y);
        ap[3] = cvt_pk_bf16(b.z, b.w);
      }
    }
    f32x4 acc[5] = {{0,0,0,0},{0,0,0,0},{0,0,0,0},{0,0,0,0},{0,0,0,0}};
#pragma unroll
    for (int ct = 0; ct < 5; ++ct)
#pragma unroll
      for (int kt = 0; kt < 4; ++kt)
        acc[ct] = __builtin_amdgcn_mfma_f32_16x16x32_bf16(af[kt], bf[ct][kt], acc[ct], 0, 0, 0);

    // --- LDS-staged epilogue (wave-private, no barrier) ---
    // C/D layout: col = lane&15, row = (lane>>4)*4 + j
    const int c0 = lane & 15;
    const int r0 = (lane >> 4) * 4;
#pragma unroll
    for (int j = 0; j < 4; ++j) {
#pragma unroll
      for (int ct = 0; ct < 4; ++ct)
        OT[wid][(r0 + j) * 68 + ct * 16 + c0] = f2bf(acc[ct][j]);
      if (c0 < 8) AT[wid][(r0 + j) * 8 + c0] = acc[4][j];
    }
    // coalesced writeback: 2 rows (256B) per instruction
    unsigned* hbu = (unsigned*)(hb + (size_t)row0 * HD);
#pragma unroll
    for (int it = 0; it < 8; ++it) {
      const int rr = it * 2 + (lane >> 5);
      const int cw = lane & 31;
      const unsigned v = *(const unsigned*)&OT[wid][rr * 68 + cw * 2];
      if (row0 + rr < N) hbu[rr * 32 + cw] = v;
    }
    {
      const int rr = lane >> 2, cc = lane & 3;
      if (row0 + rr < N) {
        a_src[(row0 + rr) * 4 + cc] = AT[wid][rr * 8 + cc];
        a_dst[(row0 + rr) * 4 + cc] = AT[wid][rr * 8 + 4 + cc];
      }
    }
  }

  // fused degree histogram over this block's edge slice
  const int per = (E + gridDim.x - 1) / gridDim.x;
  const int e0 = blockIdx.x * per;
  const int e1 = min(e0 + per, E);
  for (int e = e0 + tid; e < e1; e += 512)
    atomicAdd(&deg[ei[e]], 1);
}

// ---------------- K3a: per-block exclusive scan ----------------
__global__ void k_scanA(const int* __restrict__ deg, int* __restrict__ offs,
                        int* __restrict__ partials, int N) {
  __shared__ int wsum[16];
  const int tid = threadIdx.x, lane = tid & 63, wv = tid >> 6;
  int i = blockIdx.x * 1024 + tid;
  int v = (i < N) ? deg[i] : 0;
  int sc = v;
#pragma unroll
  for (int s = 1; s < 64; s <<= 1) {
    int t = __shfl_up(sc, s, 64);
    if (lane >= s) sc += t;
  }
  if (lane == 63) wsum[wv] = sc;
  __syncthreads();
  if (wv == 0 && lane < 16) {
    int w = wsum[lane];
    int s2 = w;
#pragma unroll
    for (int s = 1; s < 16; s <<= 1) {
      int t = __shfl_up(s2, s, 64);
      if (lane >= s) s2 += t;
    }
    wsum[lane] = s2 - w;
  }
  __syncthreads();
  int excl = sc - v + wsum[wv];
  if (i < N) offs[i] = excl;
  if (tid == 1023) partials[blockIdx.x] = excl + v;
}

// ---------------- K3b: add block bases ----------------
__global__ void k_scanB(int* __restrict__ offs, const int* __restrict__ partials, int N) {
  __shared__ int sbase;
  const int tid = threadIdx.x, b = blockIdx.x;
  if (tid < 64) {
    int acc = 0;
    for (int j = tid; j < b; j += 64) acc += partials[j];
#pragma unroll
    for (int s = 32; s >= 1; s >>= 1) acc += __shfl_xor(acc, s, 64);
    if (tid == 0) sbase = acc;
  }
  __syncthreads();
  int i = b * 1024 + tid;
  if (i < N) offs[i] += sbase;
}

// ---------------- K4: XCD-aware CSR scatter, single dispatch ----------------
__global__ void k_scatter8(const int* __restrict__ ei, int* __restrict__ offs,
                           int* __restrict__ csr, int E, int N) {
  const int xcd  = blockIdx.x & 7;
  const int grp  = blockIdx.x >> 3;
  const int ngrp = gridDim.x >> 3;
  const int step = (N + 7) >> 3;
  const int lo = xcd * step, hi = min(N, lo + step);
  const int stride = ngrp * blockDim.x;
  for (int e = grp * blockDim.x + threadIdx.x; e < E; e += stride) {
    int s = ei[e];
    if (s >= lo && s < hi) {
      int d = ei[E + e];
      int p = atomicAdd(&offs[s], 1);
      csr[p] = d;
    }
  }
}

// ---------------- K5: aggregate, scalarized serial loop ----------------
__global__ __launch_bounds__(256)
void k_agg(const int* __restrict__ offs_end, const int* __restrict__ deg,
           const int* __restrict__ csr, const float4* __restrict__ a_src4,
           const float4* __restrict__ a_dst4,
           const unsigned short* __restrict__ hb,
           float* __restrict__ out, int N) {
  __shared__ float als[4][64 * NH];
  const int lane = threadIdx.x & 63;
  const int wid  = threadIdx.x >> 6;
  const int hh = lane >> 4;
  const int wstride = gridDim.x * 4;

  for (int n0 = blockIdx.x * 4 + wid; n0 < N; n0 += wstride) {
    const int n   = __builtin_amdgcn_readfirstlane(n0);
    const int end = __builtin_amdgcn_readfirstlane(offs_end[n]);
    const int dg  = __builtin_amdgcn_readfirstlane(deg[n]);
    const int beg = end - dg;
    const float4 asv = a_src4[n];

    float s0 = 0.f, s1 = 0.f, s2 = 0.f, s3 = 0.f;
    float acc0 = 0.f, acc1 = 0.f;
    for (int base = beg; base < end; base += 64) {
      const int cnt = __builtin_amdgcn_readfirstlane(min(64, end - base));
      const bool act = lane < cnt;
      const int d = csr[act ? base + lane : beg];
      const float4 ad = a_dst4[d];
      const float p0 = act ? __expf(leaky02(asv.x + ad.x)) : 0.f;
      const float p1 = act ? __expf(leaky02(asv.y + ad.y)) : 0.f;
      const float p2 = act ? __expf(leaky02(asv.z + ad.z)) : 0.f;
      const float p3 = act ? __expf(leaky02(asv.w + ad.w)) : 0.f;
      s0 += p0; s1 += p1; s2 += p2; s3 += p3;
      *(float4*)&als[wid][lane * 4] = make_float4(p0, p1, p2, p3);

      int j = 0;
      for (; j + 8 <= cnt; j += 8) {  // scalar row bases, 8 gathers in flight
        int dds[8];
#pragma unroll
        for (int u = 0; u < 8; ++u)
          dds[u] = __builtin_amdgcn_readfirstlane(csr[base + j + u]);
        float hv[8];
#pragma unroll
        for (int u = 0; u < 8; ++u) hv[u] = bf2f(hb[(size_t)dds[u] * HD + lane]);
#pragma unroll
        for (int u = 0; u < 8; ++u) {
          const float av = als[wid][(j + u) * 4 + hh];
          if (u & 1) acc1 = fmaf(av, hv[u], acc1);
          else       acc0 = fmaf(av, hv[u], acc0);
        }
      }
      for (; j < cnt; ++j) {
        const int dd_ = __builtin_amdgcn_readfirstlane(csr[base + j]);
        const float av = als[wid][j * 4 + hh];
        acc0 = fmaf(av, bf2f(hb[(size_t)dd_ * HD + lane]), acc0);
      }
    }
#pragma unroll
    for (int s = 1; s < 64; s <<= 1) {
      s0 += __shfl_xor(s0, s, 64); s1 += __shfl_xor(s1, s, 64);
      s2 += __shfl_xor(s2, s, 64); s3 += __shfl_xor(s3, s, 64);
    }
    const float sh = (hh == 0) ? s0 : (hh == 1) ? s1 : (hh == 2) ? s2 : s3;
    out[(size_t)n * HD + lane] = (acc0 + acc1) * (1.f / (sh + 1e-16f));
  }
}

extern "C" void kernel_launch(void* const* d_in, const int* in_sizes, int n_in,
                              void* d_out, int out_size, void* d_ws, size_t ws_size,
                              hipStream_t stream) {
  const float* x    = (const float*)d_in[0];
  const int*   ei   = (const int*)d_in[1];
  const float* Wlin = (const float*)d_in[2];
  const float* Watt = (const float*)d_in[3];
  float* out = (float*)d_out;

  const int N = in_sizes[0] / DIN;
  const int E = in_sizes[1] / 2;

  char* ws = (char*)d_ws;
  size_t off = 0;
  unsigned short* hb = (unsigned short*)(ws + off); off += (size_t)N * HD * sizeof(unsigned short);
  float* a_src  = (float*)(ws + off); off += (size_t)N * NH * sizeof(float);
  float* a_dst  = (float*)(ws + off); off += (size_t)N * NH * sizeof(float);
  int*   deg    = (int*)(ws + off);   off += (size_t)N * sizeof(int);
  int*   offs   = (int*)(ws + off);   off += ((size_t)N + 1) * sizeof(int);
  int*   csr    = (int*)(ws + off);   off += (size_t)E * sizeof(int);
  int*   parts  = (int*)(ws + off);   off += 128 * sizeof(int);

  hipMemsetAsync(deg, 0, (size_t)N * sizeof(int), stream);

  hipLaunchKernelGGL(k_linear, dim3((N + 255) / 256), dim3(512), 0, stream,
                     x, Wlin, Watt, hb, a_src, a_dst, N, ei, deg, E);

  const int SB = (N + 1023) / 1024;
  hipLaunchKernelGGL(k_scanA, dim3(SB), dim3(1024), 0, stream, deg, offs, parts, N);
  hipLaunchKernelGGL(k_scanB, dim3(SB), dim3(1024), 0, stream, offs, parts, N);

  hipLaunchKernelGGL(k_scatter8, dim3(2048), dim3(256), 0, stream,
                     ei, offs, csr, E, N);

  // offs[n] == segment end now
  hipLaunchKernelGGL(k_agg, dim3(4096), dim3(256), 0, stream,
                     offs, deg, csr, (const float4*)a_src, (const float4*)a_dst, hb, out, N);
}